// Round 1
// baseline (1107.362 us; speedup 1.0000x reference)
//
#include <hip/hip_runtime.h>
#include <math.h>

#define D_MODEL 512
#define NHEAD   8
#define HD      64
#define T_SEQ   2048
#define BATCH   4
#define M_ROWS  (BATCH * T_SEQ)   // 8192

// ---------------------------------------------------------------------------
// Kernel 1: QKV projection.  C(8192 x 1536) = x(8192x512) @ in_proj_w^T + b
// in_proj_w is (1536,512) row-major => C[m,n] = sum_k x[m,k]*w[n,k]  (NT gemm)
// Output scattered head-major: q/k/v each (B,H,T,64) fp32 in workspace.
// 64x64 tile, 256 threads, 4x4 micro-tile, K-transposed LDS (float4 reads).
// ---------------------------------------------------------------------------
__global__ __launch_bounds__(256) void qkv_gemm(
    const float* __restrict__ x, const float* __restrict__ w,
    const float* __restrict__ bias,
    float* __restrict__ qo, float* __restrict__ ko, float* __restrict__ vo)
{
    __shared__ float As[16][68];   // [k][row], +4 pad keeps 16B alignment
    __shared__ float Bs[16][68];

    const int tid  = threadIdx.x;
    const int tx   = tid & 15, ty = tid >> 4;
    const int row0 = blockIdx.x * 64;           // m tile
    const int col0 = blockIdx.y * 64;           // n tile in [0,1536)
    const int lr   = tid >> 2;                  // 0..63 loader row
    const int lk   = (tid & 3) << 2;            // 0,4,8,12 loader k

    const float* arow = x + (size_t)(row0 + lr) * D_MODEL + lk;
    const float* brow = w + (size_t)(col0 + lr) * D_MODEL + lk;

    float acc[4][4] = {};

    for (int k0 = 0; k0 < D_MODEL; k0 += 16) {
        float4 a4 = *(const float4*)(arow + k0);
        float4 b4 = *(const float4*)(brow + k0);
        __syncthreads();
        As[lk+0][lr] = a4.x; As[lk+1][lr] = a4.y; As[lk+2][lr] = a4.z; As[lk+3][lr] = a4.w;
        Bs[lk+0][lr] = b4.x; Bs[lk+1][lr] = b4.y; Bs[lk+2][lr] = b4.z; Bs[lk+3][lr] = b4.w;
        __syncthreads();
#pragma unroll
        for (int kk = 0; kk < 16; ++kk) {
            float4 a = *(const float4*)&As[kk][ty << 2];
            float4 b = *(const float4*)&Bs[kk][tx << 2];
            float af[4] = {a.x, a.y, a.z, a.w};
            float bf[4] = {b.x, b.y, b.z, b.w};
#pragma unroll
            for (int ii = 0; ii < 4; ++ii)
#pragma unroll
                for (int jj = 0; jj < 4; ++jj)
                    acc[ii][jj] += af[ii] * bf[jj];
        }
    }

    // epilogue: col0 is 64-aligned -> whole block maps to one of q/k/v, one head
    const int part = col0 >> 9;                 // 0=q 1=k 2=v
    const int head = (col0 & 511) >> 6;
    float* dst = (part == 0) ? qo : ((part == 1) ? ko : vo);
    const int b  = row0 >> 11;                  // 2048 % 64 == 0 -> uniform
    const int t0 = row0 & 2047;
    const int d0 = tx << 2;
    const float4 bb = *(const float4*)&bias[col0 + d0];

#pragma unroll
    for (int ii = 0; ii < 4; ++ii) {
        const int t = t0 + (ty << 2) + ii;
        float4 r;
        r.x = acc[ii][0] + bb.x;
        r.y = acc[ii][1] + bb.y;
        r.z = acc[ii][2] + bb.z;
        r.w = acc[ii][3] + bb.w;
        *(float4*)&dst[((((size_t)b << 3) + head) * T_SEQ + t) * HD + d0] = r;
    }
}

// ---------------------------------------------------------------------------
// Kernel 2: periodic-sparse attention, gather form.
// One wave (64 lanes) per query row (b,h,i); lane = head dim.
// Allowed keys: j = i, i-P, i-2P, ... >= 0.  Online softmax.
// ---------------------------------------------------------------------------
__global__ __launch_bounds__(256) void attn_sparse(
    const float* __restrict__ q, const float* __restrict__ k,
    const float* __restrict__ v, const int* __restrict__ periods,
    float* __restrict__ o)
{
    const int wave = threadIdx.x >> 6;
    const int lane = threadIdx.x & 63;
    const int linear = blockIdx.x * 4 + wave;       // b*H*T + h*T + i
    const int i  = linear & (T_SEQ - 1);
    const int bh = linear >> 11;                    // b*8 + h

    int P = periods[bh];
    if (P < 1) P = 1;

    const float  ql    = q[((size_t)bh * T_SEQ + i) * HD + lane];
    const float* kbase = k + (size_t)bh * T_SEQ * HD + lane;
    const float* vbase = v + (size_t)bh * T_SEQ * HD + lane;

    float m_max = -1e30f, l_sum = 0.f, acc = 0.f;
    for (int j = i; j >= 0; j -= P) {
        const float kl = kbase[j * HD];
        const float vl = vbase[j * HD];
        float s = ql * kl;
#pragma unroll
        for (int off = 32; off; off >>= 1) s += __shfl_xor(s, off);
        s *= 0.125f;                                // 1/sqrt(64)
        const float nm = fmaxf(m_max, s);
        const float sc = __expf(m_max - nm);        // first iter: exp(-huge)=0
        const float p  = __expf(s - nm);
        l_sum = l_sum * sc + p;
        acc   = acc   * sc + p * vl;
        m_max = nm;
    }
    o[((size_t)bh * T_SEQ + i) * HD + lane] = acc / l_sum;
}

// ---------------------------------------------------------------------------
// Kernel 3: out projection.  out(8192x512) = attn @ out_w^T + out_b
// attn stored (B,H,T,64); logical A[m, k] = attn[b, k>>6, t, k&63], m=b*T+t.
// ---------------------------------------------------------------------------
__global__ __launch_bounds__(256) void out_gemm(
    const float* __restrict__ attn, const float* __restrict__ w,
    const float* __restrict__ bias, float* __restrict__ out)
{
    __shared__ float As[16][68];
    __shared__ float Bs[16][68];

    const int tid  = threadIdx.x;
    const int tx   = tid & 15, ty = tid >> 4;
    const int row0 = blockIdx.x * 64;
    const int col0 = blockIdx.y * 64;               // n in [0,512)
    const int lr   = tid >> 2;
    const int lk   = (tid & 3) << 2;

    const int m = row0 + lr;
    const int b = m >> 11, t = m & 2047;
    const float* brow = w + (size_t)(col0 + lr) * D_MODEL + lk;

    float acc[4][4] = {};

    for (int k0 = 0; k0 < D_MODEL; k0 += 16) {
        const int kidx = k0 + lk;                   // 16-chunk never crosses a head
        float4 a4 = *(const float4*)(attn +
            ((((size_t)b << 3) + (kidx >> 6)) * T_SEQ + t) * HD + (kidx & 63));
        float4 b4 = *(const float4*)(brow + k0);
        __syncthreads();
        As[lk+0][lr] = a4.x; As[lk+1][lr] = a4.y; As[lk+2][lr] = a4.z; As[lk+3][lr] = a4.w;
        Bs[lk+0][lr] = b4.x; Bs[lk+1][lr] = b4.y; Bs[lk+2][lr] = b4.z; Bs[lk+3][lr] = b4.w;
        __syncthreads();
#pragma unroll
        for (int kk = 0; kk < 16; ++kk) {
            float4 a = *(const float4*)&As[kk][ty << 2];
            float4 b = *(const float4*)&Bs[kk][tx << 2];
            float af[4] = {a.x, a.y, a.z, a.w};
            float bf[4] = {b.x, b.y, b.z, b.w};
#pragma unroll
            for (int ii = 0; ii < 4; ++ii)
#pragma unroll
                for (int jj = 0; jj < 4; ++jj)
                    acc[ii][jj] += af[ii] * bf[jj];
        }
    }

    const int d0 = tx << 2;
    const float4 bb = *(const float4*)&bias[col0 + d0];
#pragma unroll
    for (int ii = 0; ii < 4; ++ii) {
        const int mr = row0 + (ty << 2) + ii;
        float4 r;
        r.x = acc[ii][0] + bb.x;
        r.y = acc[ii][1] + bb.y;
        r.z = acc[ii][2] + bb.z;
        r.w = acc[ii][3] + bb.w;
        *(float4*)&out[(size_t)mr * D_MODEL + col0 + d0] = r;
    }
}

// ---------------------------------------------------------------------------
extern "C" void kernel_launch(void* const* d_in, const int* in_sizes, int n_in,
                              void* d_out, int out_size, void* d_ws, size_t ws_size,
                              hipStream_t stream)
{
    const float* x        = (const float*)d_in[0];
    const int*   periods  = (const int*)  d_in[1];
    const float* in_w     = (const float*)d_in[2];
    const float* in_b     = (const float*)d_in[3];
    const float* out_w    = (const float*)d_in[4];
    const float* out_b    = (const float*)d_in[5];
    float*       out      = (float*)d_out;

    const size_t TENS = (size_t)BATCH * NHEAD * T_SEQ * HD;   // 4,194,304 floats
    float* q  = (float*)d_ws;
    float* k  = q + TENS;
    float* v  = k + TENS;
    float* ao = v + TENS;

    // 1) QKV projection -> head-major q,k,v
    dim3 g1(M_ROWS / 64, (3 * D_MODEL) / 64);   // 128 x 24
    qkv_gemm<<<g1, 256, 0, stream>>>(x, in_w, in_b, q, k, v);

    // 2) periodic-sparse attention (one wave per query row)
    const int rows = BATCH * NHEAD * T_SEQ;     // 65536
    attn_sparse<<<rows / 4, 256, 0, stream>>>(q, k, v, periods, ao);

    // 3) out projection
    dim3 g3(M_ROWS / 64, D_MODEL / 64);         // 128 x 8
    out_gemm<<<g3, 256, 0, stream>>>(ao, out_w, out_b, out);
}

// Round 2
// 951.873 us; speedup vs baseline: 1.1634x; 1.1634x over previous
//
#include <hip/hip_runtime.h>
#include <math.h>

#define D_MODEL 512
#define NHEAD   8
#define HD      64
#define T_SEQ   2048
#define BATCH   4
#define M_ROWS  (BATCH * T_SEQ)   // 8192

// ---------------------------------------------------------------------------
// Kernel 1: QKV projection.  C(8192 x 1536) = x(8192x512) @ in_proj_w^T + b
// Output scattered head-major: q/k/v each (B,H,T,64) fp32 in workspace.
// ---------------------------------------------------------------------------
__global__ __launch_bounds__(256) void qkv_gemm(
    const float* __restrict__ x, const float* __restrict__ w,
    const float* __restrict__ bias,
    float* __restrict__ qo, float* __restrict__ ko, float* __restrict__ vo)
{
    __shared__ float As[16][68];   // [k][row], +4 pad keeps 16B alignment
    __shared__ float Bs[16][68];

    const int tid  = threadIdx.x;
    const int tx   = tid & 15, ty = tid >> 4;
    const int row0 = blockIdx.x * 64;           // m tile
    const int col0 = blockIdx.y * 64;           // n tile in [0,1536)
    const int lr   = tid >> 2;                  // 0..63 loader row
    const int lk   = (tid & 3) << 2;            // 0,4,8,12 loader k

    const float* arow = x + (size_t)(row0 + lr) * D_MODEL + lk;
    const float* brow = w + (size_t)(col0 + lr) * D_MODEL + lk;

    float acc[4][4] = {};

    for (int k0 = 0; k0 < D_MODEL; k0 += 16) {
        float4 a4 = *(const float4*)(arow + k0);
        float4 b4 = *(const float4*)(brow + k0);
        __syncthreads();
        As[lk+0][lr] = a4.x; As[lk+1][lr] = a4.y; As[lk+2][lr] = a4.z; As[lk+3][lr] = a4.w;
        Bs[lk+0][lr] = b4.x; Bs[lk+1][lr] = b4.y; Bs[lk+2][lr] = b4.z; Bs[lk+3][lr] = b4.w;
        __syncthreads();
#pragma unroll
        for (int kk = 0; kk < 16; ++kk) {
            float4 a = *(const float4*)&As[kk][ty << 2];
            float4 b = *(const float4*)&Bs[kk][tx << 2];
            float af[4] = {a.x, a.y, a.z, a.w};
            float bf[4] = {b.x, b.y, b.z, b.w};
#pragma unroll
            for (int ii = 0; ii < 4; ++ii)
#pragma unroll
                for (int jj = 0; jj < 4; ++jj)
                    acc[ii][jj] += af[ii] * bf[jj];
        }
    }

    const int part = col0 >> 9;                 // 0=q 1=k 2=v
    const int head = (col0 & 511) >> 6;
    float* dst = (part == 0) ? qo : ((part == 1) ? ko : vo);
    const int b  = row0 >> 11;
    const int t0 = row0 & 2047;
    const int d0 = tx << 2;
    const float4 bb = *(const float4*)&bias[col0 + d0];

#pragma unroll
    for (int ii = 0; ii < 4; ++ii) {
        const int t = t0 + (ty << 2) + ii;
        float4 r;
        r.x = acc[ii][0] + bb.x;
        r.y = acc[ii][1] + bb.y;
        r.z = acc[ii][2] + bb.z;
        r.w = acc[ii][3] + bb.w;
        *(float4*)&dst[((((size_t)b << 3) + head) * T_SEQ + t) * HD + d0] = r;
    }
}

// ---------------------------------------------------------------------------
// Kernel 2: periodic-sparse attention, gather form, 8-wide key batching.
// One wave per query row (b,h,i); lane = head dim.  Allowed keys:
// j = i, i-P, i-2P, ... >= 0.  Online softmax updated once per 8 keys:
// the 8 shuffle-reduction trees are independent and pipeline, and the
// dependent max/exp/rescale chain is paid once per round instead of per key.
// ---------------------------------------------------------------------------
__global__ __launch_bounds__(256) void attn_sparse(
    const float* __restrict__ q, const float* __restrict__ k,
    const float* __restrict__ v, const int* __restrict__ periods,
    float* __restrict__ o)
{
    const int wave = threadIdx.x >> 6;
    const int lane = threadIdx.x & 63;
    const int linear = blockIdx.x * 4 + wave;       // b*H*T + h*T + i
    const int i  = linear & (T_SEQ - 1);
    const int bh = linear >> 11;                    // b*8 + h

    int P = periods[bh];
    if (P < 1) P = 1;

    const float  ql    = q[((size_t)bh * T_SEQ + i) * HD + lane] * 0.125f; // fold 1/sqrt(64)
    const float* kbase = k + (size_t)bh * T_SEQ * HD + lane;
    const float* vbase = v + (size_t)bh * T_SEQ * HD + lane;

    float m_max = -1e30f, l_sum = 0.f, acc = 0.f;
    int nk = i / P + 1;                 // number of allowed keys
    const int stride = P * HD;
    const float* kp = kbase + (size_t)i * HD;
    const float* vp = vbase + (size_t)i * HD;

    while (nk >= 8) {
        float kv[8], vv[8], s[8];
#pragma unroll
        for (int u = 0; u < 8; ++u) {
            kv[u] = kp[-(u * stride)];
            vv[u] = vp[-(u * stride)];
        }
#pragma unroll
        for (int u = 0; u < 8; ++u) {
            s[u] = ql * kv[u];
#pragma unroll
            for (int off = 32; off; off >>= 1) s[u] += __shfl_xor(s[u], off);
        }
        // batched online-softmax update (one dependent chain per 8 keys)
        float smax = fmaxf(fmaxf(fmaxf(s[0], s[1]), fmaxf(s[2], s[3])),
                           fmaxf(fmaxf(s[4], s[5]), fmaxf(s[6], s[7])));
        const float nm = fmaxf(m_max, smax);
        const float sc = __expf(m_max - nm);
        float p[8];
#pragma unroll
        for (int u = 0; u < 8; ++u) p[u] = __expf(s[u] - nm);
        const float psum = ((p[0] + p[1]) + (p[2] + p[3])) +
                           ((p[4] + p[5]) + (p[6] + p[7]));
        const float pv = ((p[0] * vv[0] + p[1] * vv[1]) + (p[2] * vv[2] + p[3] * vv[3])) +
                         ((p[4] * vv[4] + p[5] * vv[5]) + (p[6] * vv[6] + p[7] * vv[7]));
        l_sum = l_sum * sc + psum;
        acc   = acc   * sc + pv;
        m_max = nm;
        kp -= 8 * stride;
        vp -= 8 * stride;
        nk -= 8;
    }

    // tail: up to 7 keys
    for (int u = 0; u < nk; ++u) {
        const float kl = kp[-(u * stride)];
        const float vl = vp[-(u * stride)];
        float s = ql * kl;
#pragma unroll
        for (int off = 32; off; off >>= 1) s += __shfl_xor(s, off);
        const float nm = fmaxf(m_max, s);
        const float sc = __expf(m_max - nm);
        const float p  = __expf(s - nm);
        l_sum = l_sum * sc + p;
        acc   = acc   * sc + p * vl;
        m_max = nm;
    }

    o[((size_t)bh * T_SEQ + i) * HD + lane] = acc / l_sum;
}

// ---------------------------------------------------------------------------
// Kernel 3: out projection.  out(8192x512) = attn @ out_w^T + out_b
// ---------------------------------------------------------------------------
__global__ __launch_bounds__(256) void out_gemm(
    const float* __restrict__ attn, const float* __restrict__ w,
    const float* __restrict__ bias, float* __restrict__ out)
{
    __shared__ float As[16][68];
    __shared__ float Bs[16][68];

    const int tid  = threadIdx.x;
    const int tx   = tid & 15, ty = tid >> 4;
    const int row0 = blockIdx.x * 64;
    const int col0 = blockIdx.y * 64;               // n in [0,512)
    const int lr   = tid >> 2;
    const int lk   = (tid & 3) << 2;

    const int m = row0 + lr;
    const int b = m >> 11, t = m & 2047;
    const float* brow = w + (size_t)(col0 + lr) * D_MODEL + lk;

    float acc[4][4] = {};

    for (int k0 = 0; k0 < D_MODEL; k0 += 16) {
        const int kidx = k0 + lk;                   // 16-chunk never crosses a head
        float4 a4 = *(const float4*)(attn +
            ((((size_t)b << 3) + (kidx >> 6)) * T_SEQ + t) * HD + (kidx & 63));
        float4 b4 = *(const float4*)(brow + k0);
        __syncthreads();
        As[lk+0][lr] = a4.x; As[lk+1][lr] = a4.y; As[lk+2][lr] = a4.z; As[lk+3][lr] = a4.w;
        Bs[lk+0][lr] = b4.x; Bs[lk+1][lr] = b4.y; Bs[lk+2][lr] = b4.z; Bs[lk+3][lr] = b4.w;
        __syncthreads();
#pragma unroll
        for (int kk = 0; kk < 16; ++kk) {
            float4 a = *(const float4*)&As[kk][ty << 2];
            float4 b = *(const float4*)&Bs[kk][tx << 2];
            float af[4] = {a.x, a.y, a.z, a.w};
            float bf[4] = {b.x, b.y, b.z, b.w};
#pragma unroll
            for (int ii = 0; ii < 4; ++ii)
#pragma unroll
                for (int jj = 0; jj < 4; ++jj)
                    acc[ii][jj] += af[ii] * bf[jj];
        }
    }

    const int d0 = tx << 2;
    const float4 bb = *(const float4*)&bias[col0 + d0];
#pragma unroll
    for (int ii = 0; ii < 4; ++ii) {
        const int mr = row0 + (ty << 2) + ii;
        float4 r;
        r.x = acc[ii][0] + bb.x;
        r.y = acc[ii][1] + bb.y;
        r.z = acc[ii][2] + bb.z;
        r.w = acc[ii][3] + bb.w;
        *(float4*)&out[(size_t)mr * D_MODEL + col0 + d0] = r;
    }
}

// ---------------------------------------------------------------------------
extern "C" void kernel_launch(void* const* d_in, const int* in_sizes, int n_in,
                              void* d_out, int out_size, void* d_ws, size_t ws_size,
                              hipStream_t stream)
{
    const float* x        = (const float*)d_in[0];
    const int*   periods  = (const int*)  d_in[1];
    const float* in_w     = (const float*)d_in[2];
    const float* in_b     = (const float*)d_in[3];
    const float* out_w    = (const float*)d_in[4];
    const float* out_b    = (const float*)d_in[5];
    float*       out      = (float*)d_out;

    const size_t TENS = (size_t)BATCH * NHEAD * T_SEQ * HD;   // 4,194,304 floats
    float* q  = (float*)d_ws;
    float* k  = q + TENS;
    float* v  = k + TENS;
    float* ao = v + TENS;

    dim3 g1(M_ROWS / 64, (3 * D_MODEL) / 64);   // 128 x 24
    qkv_gemm<<<g1, 256, 0, stream>>>(x, in_w, in_b, q, k, v);

    const int rows = BATCH * NHEAD * T_SEQ;     // 65536
    attn_sparse<<<rows / 4, 256, 0, stream>>>(q, k, v, periods, ao);

    dim3 g3(M_ROWS / 64, D_MODEL / 64);         // 128 x 8
    out_gemm<<<g3, 256, 0, stream>>>(ao, out_w, out_b, out);
}

// Round 3
// 506.507 us; speedup vs baseline: 2.1863x; 1.8793x over previous
//
#include <hip/hip_runtime.h>
#include <math.h>

#define D_MODEL 512
#define NHEAD   8
#define HD      64
#define T_SEQ   2048
#define BATCH   4
#define M_ROWS  (BATCH * T_SEQ)   // 8192

// ---------------------------------------------------------------------------
// Kernel 1: QKV projection.  C(8192 x 1536) = x(8192x512) @ in_proj_w^T + b
// Output scattered head-major: q/k/v each (B,H,T,64) fp32 in workspace.
// ---------------------------------------------------------------------------
__global__ __launch_bounds__(256) void qkv_gemm(
    const float* __restrict__ x, const float* __restrict__ w,
    const float* __restrict__ bias,
    float* __restrict__ qo, float* __restrict__ ko, float* __restrict__ vo)
{
    __shared__ float As[16][68];
    __shared__ float Bs[16][68];

    const int tid  = threadIdx.x;
    const int tx   = tid & 15, ty = tid >> 4;
    const int row0 = blockIdx.x * 64;
    const int col0 = blockIdx.y * 64;
    const int lr   = tid >> 2;
    const int lk   = (tid & 3) << 2;

    const float* arow = x + (size_t)(row0 + lr) * D_MODEL + lk;
    const float* brow = w + (size_t)(col0 + lr) * D_MODEL + lk;

    float acc[4][4] = {};

    for (int k0 = 0; k0 < D_MODEL; k0 += 16) {
        float4 a4 = *(const float4*)(arow + k0);
        float4 b4 = *(const float4*)(brow + k0);
        __syncthreads();
        As[lk+0][lr] = a4.x; As[lk+1][lr] = a4.y; As[lk+2][lr] = a4.z; As[lk+3][lr] = a4.w;
        Bs[lk+0][lr] = b4.x; Bs[lk+1][lr] = b4.y; Bs[lk+2][lr] = b4.z; Bs[lk+3][lr] = b4.w;
        __syncthreads();
#pragma unroll
        for (int kk = 0; kk < 16; ++kk) {
            float4 a = *(const float4*)&As[kk][ty << 2];
            float4 b = *(const float4*)&Bs[kk][tx << 2];
            float af[4] = {a.x, a.y, a.z, a.w};
            float bf[4] = {b.x, b.y, b.z, b.w};
#pragma unroll
            for (int ii = 0; ii < 4; ++ii)
#pragma unroll
                for (int jj = 0; jj < 4; ++jj)
                    acc[ii][jj] += af[ii] * bf[jj];
        }
    }

    const int part = col0 >> 9;
    const int head = (col0 & 511) >> 6;
    float* dst = (part == 0) ? qo : ((part == 1) ? ko : vo);
    const int b  = row0 >> 11;
    const int t0 = row0 & 2047;
    const int d0 = tx << 2;
    const float4 bb = *(const float4*)&bias[col0 + d0];

#pragma unroll
    for (int ii = 0; ii < 4; ++ii) {
        const int t = t0 + (ty << 2) + ii;
        float4 r;
        r.x = acc[ii][0] + bb.x;
        r.y = acc[ii][1] + bb.y;
        r.z = acc[ii][2] + bb.z;
        r.w = acc[ii][3] + bb.w;
        *(float4*)&dst[((((size_t)b << 3) + head) * T_SEQ + t) * HD + d0] = r;
    }
}

// ---------------------------------------------------------------------------
// Kernel 2: residue-class flash attention.
// Queries with i % P == r attend exactly the causal prefix of the subsequence
// {r, r+P, r+2P, ...} -> dense causal flash attention in subsequence space.
// Block: 256 threads, 64-query tile x 64-key tiles, 4x4 register micro-tiles.
// LDS: Q^T and K^T ([d][m], b128-friendly), V row-major; K buffer is reused
// for P̃^T between score and PV phases.
// ---------------------------------------------------------------------------
__global__ __launch_bounds__(256) void attn_rc(
    const float* __restrict__ q, const float* __restrict__ k,
    const float* __restrict__ v, const int* __restrict__ periods,
    float* __restrict__ o)
{
    __shared__ float Qs[64][68];
    __shared__ float KPs[64][68];   // K^T during scores; P̃^T during PV
    __shared__ float Vs[64][68];

    const int bh = blockIdx.y;
    int P = periods[bh]; if (P < 1) P = 1;
    const int q0 = T_SEQ / P, rem = T_SEQ % P;   // L_r = q0+1 (r<rem) else q0
    const int nt_hi = (q0 + 64) >> 6;            // ceil((q0+1)/64)
    const int nt_lo = (q0 + 63) >> 6;            // ceil(q0/64)
    int t = blockIdx.x;
    int r, mt, Lr;
    const int hi_total = rem * nt_hi;
    if (t < hi_total) {
        r = t / nt_hi; mt = t - r * nt_hi; Lr = q0 + 1;
    } else {
        t -= hi_total;
        if (t >= (P - rem) * nt_lo) return;
        const int rr = t / nt_lo;
        r = rem + rr; mt = t - rr * nt_lo; Lr = q0;
    }
    const int m0 = mt << 6;

    const int tid  = threadIdx.x;
    const int tx   = tid & 15, ty = tid >> 4;
    const int srow = tid >> 2;            // staging row 0..63
    const int scol = (tid & 3) << 2;      // 0,4,8,12

    const float* hq = q + (size_t)bh * T_SEQ * HD;
    const float* hk = k + (size_t)bh * T_SEQ * HD;
    const float* hv = v + (size_t)bh * T_SEQ * HD;

    // ---- stage Q tile transposed, scale 1/sqrt(64) folded in ----
    {
        int m = m0 + srow; if (m > Lr - 1) m = Lr - 1;
        const float* src = hq + (size_t)(r + m * P) * HD;
#pragma unroll
        for (int rep = 0; rep < 4; ++rep) {
            const int d = scol + (rep << 4);
            float4 a = *(const float4*)(src + d);
            Qs[d+0][srow] = a.x * 0.125f;
            Qs[d+1][srow] = a.y * 0.125f;
            Qs[d+2][srow] = a.z * 0.125f;
            Qs[d+3][srow] = a.w * 0.125f;
        }
    }

    float O[4][4] = {};
    float l_i[4] = {0.f, 0.f, 0.f, 0.f};
    float m_i[4] = {-1e30f, -1e30f, -1e30f, -1e30f};

    for (int kt = 0; kt <= mt; ++kt) {
        const int km0 = kt << 6;

        // ---- stage K^T and V (loads issued before the barrier) ----
        int mk = km0 + srow; if (mk > Lr - 1) mk = Lr - 1;
        const size_t g = (size_t)(r + mk * P) * HD;
        float4 ka[4], va[4];
#pragma unroll
        for (int rep = 0; rep < 4; ++rep) {
            const int d = scol + (rep << 4);
            ka[rep] = *(const float4*)(hk + g + d);
            va[rep] = *(const float4*)(hv + g + d);
        }
        __syncthreads();            // prev PV done reading KPs/Vs
#pragma unroll
        for (int rep = 0; rep < 4; ++rep) {
            const int d = scol + (rep << 4);
            KPs[d+0][srow] = ka[rep].x;
            KPs[d+1][srow] = ka[rep].y;
            KPs[d+2][srow] = ka[rep].z;
            KPs[d+3][srow] = ka[rep].w;
            *(float4*)&Vs[srow][d] = va[rep];
        }
        __syncthreads();

        // ---- scores: acc[i][j] = sum_d Q^T[d][ty4+i] * K^T[d][tx4+j] ----
        float acc[4][4] = {};
#pragma unroll 8
        for (int d = 0; d < 64; ++d) {
            float4 qv = *(const float4*)&Qs[d][ty << 2];
            float4 kv = *(const float4*)&KPs[d][tx << 2];
            float qa[4] = {qv.x, qv.y, qv.z, qv.w};
            float kb[4] = {kv.x, kv.y, kv.z, kv.w};
#pragma unroll
            for (int i = 0; i < 4; ++i)
#pragma unroll
                for (int j = 0; j < 4; ++j)
                    acc[i][j] += qa[i] * kb[j];
        }

        // causal mask (only bites on the diagonal tile)
#pragma unroll
        for (int i = 0; i < 4; ++i) {
            const int sqm = m0 + (ty << 2) + i;
#pragma unroll
            for (int j = 0; j < 4; ++j) {
                const int skm = km0 + (tx << 2) + j;
                if (skm > sqm) acc[i][j] = -1e30f;
            }
        }

        // ---- online softmax (8 shuffles per row per 64-key tile) ----
        float p[4][4], sc[4];
#pragma unroll
        for (int i = 0; i < 4; ++i) {
            float lm = fmaxf(fmaxf(acc[i][0], acc[i][1]),
                             fmaxf(acc[i][2], acc[i][3]));
            lm = fmaxf(lm, __shfl_xor(lm, 1));
            lm = fmaxf(lm, __shfl_xor(lm, 2));
            lm = fmaxf(lm, __shfl_xor(lm, 4));
            lm = fmaxf(lm, __shfl_xor(lm, 8));
            const float nm = fmaxf(m_i[i], lm);
            sc[i] = __expf(m_i[i] - nm);
            m_i[i] = nm;
            float ps = 0.f;
#pragma unroll
            for (int j = 0; j < 4; ++j) {
                p[i][j] = __expf(acc[i][j] - nm);
                ps += p[i][j];
            }
            ps += __shfl_xor(ps, 1);
            ps += __shfl_xor(ps, 2);
            ps += __shfl_xor(ps, 4);
            ps += __shfl_xor(ps, 8);
            l_i[i] = l_i[i] * sc[i] + ps;
        }

        __syncthreads();            // done reading K^T
        // write P̃^T into the K buffer: KPs[km][qm]
#pragma unroll
        for (int j = 0; j < 4; ++j)
#pragma unroll
            for (int i = 0; i < 4; ++i)
                KPs[(tx << 2) + j][(ty << 2) + i] = p[i][j];
        __syncthreads();

        // ---- O = O*sc + P̃·V ----
#pragma unroll
        for (int i = 0; i < 4; ++i)
#pragma unroll
            for (int j = 0; j < 4; ++j)
                O[i][j] *= sc[i];

#pragma unroll 4
        for (int km = 0; km < 64; ++km) {
            float4 pv = *(const float4*)&KPs[km][ty << 2];
            float4 vv = *(const float4*)&Vs[km][tx << 2];
            float pa[4] = {pv.x, pv.y, pv.z, pv.w};
            float vb[4] = {vv.x, vv.y, vv.z, vv.w};
#pragma unroll
            for (int i = 0; i < 4; ++i)
#pragma unroll
                for (int j = 0; j < 4; ++j)
                    O[i][j] += pa[i] * vb[j];
        }
    }

    // ---- store (valid subsequence rows only) ----
#pragma unroll
    for (int i = 0; i < 4; ++i) {
        const int m = m0 + (ty << 2) + i;
        if (m < Lr) {
            const float inv = 1.f / l_i[i];
            float4 rr;
            rr.x = O[i][0] * inv; rr.y = O[i][1] * inv;
            rr.z = O[i][2] * inv; rr.w = O[i][3] * inv;
            *(float4*)&o[((size_t)bh * T_SEQ + (r + m * P)) * HD + (tx << 2)] = rr;
        }
    }
}

// ---------------------------------------------------------------------------
// Kernel 3: out projection.  out(8192x512) = attn @ out_w^T + out_b
// ---------------------------------------------------------------------------
__global__ __launch_bounds__(256) void out_gemm(
    const float* __restrict__ attn, const float* __restrict__ w,
    const float* __restrict__ bias, float* __restrict__ out)
{
    __shared__ float As[16][68];
    __shared__ float Bs[16][68];

    const int tid  = threadIdx.x;
    const int tx   = tid & 15, ty = tid >> 4;
    const int row0 = blockIdx.x * 64;
    const int col0 = blockIdx.y * 64;
    const int lr   = tid >> 2;
    const int lk   = (tid & 3) << 2;

    const int m = row0 + lr;
    const int b = m >> 11, t = m & 2047;
    const float* brow = w + (size_t)(col0 + lr) * D_MODEL + lk;

    float acc[4][4] = {};

    for (int k0 = 0; k0 < D_MODEL; k0 += 16) {
        const int kidx = k0 + lk;
        float4 a4 = *(const float4*)(attn +
            ((((size_t)b << 3) + (kidx >> 6)) * T_SEQ + t) * HD + (kidx & 63));
        float4 b4 = *(const float4*)(brow + k0);
        __syncthreads();
        As[lk+0][lr] = a4.x; As[lk+1][lr] = a4.y; As[lk+2][lr] = a4.z; As[lk+3][lr] = a4.w;
        Bs[lk+0][lr] = b4.x; Bs[lk+1][lr] = b4.y; Bs[lk+2][lr] = b4.z; Bs[lk+3][lr] = b4.w;
        __syncthreads();
#pragma unroll
        for (int kk = 0; kk < 16; ++kk) {
            float4 a = *(const float4*)&As[kk][ty << 2];
            float4 b = *(const float4*)&Bs[kk][tx << 2];
            float af[4] = {a.x, a.y, a.z, a.w};
            float bf[4] = {b.x, b.y, b.z, b.w};
#pragma unroll
            for (int ii = 0; ii < 4; ++ii)
#pragma unroll
                for (int jj = 0; jj < 4; ++jj)
                    acc[ii][jj] += af[ii] * bf[jj];
        }
    }

    const int d0 = tx << 2;
    const float4 bb = *(const float4*)&bias[col0 + d0];
#pragma unroll
    for (int ii = 0; ii < 4; ++ii) {
        const int mr = row0 + (ty << 2) + ii;
        float4 r;
        r.x = acc[ii][0] + bb.x;
        r.y = acc[ii][1] + bb.y;
        r.z = acc[ii][2] + bb.z;
        r.w = acc[ii][3] + bb.w;
        *(float4*)&out[(size_t)mr * D_MODEL + col0 + d0] = r;
    }
}

// ---------------------------------------------------------------------------
extern "C" void kernel_launch(void* const* d_in, const int* in_sizes, int n_in,
                              void* d_out, int out_size, void* d_ws, size_t ws_size,
                              hipStream_t stream)
{
    const float* x        = (const float*)d_in[0];
    const int*   periods  = (const int*)  d_in[1];
    const float* in_w     = (const float*)d_in[2];
    const float* in_b     = (const float*)d_in[3];
    const float* out_w    = (const float*)d_in[4];
    const float* out_b    = (const float*)d_in[5];
    float*       out      = (float*)d_out;

    const size_t TENS = (size_t)BATCH * NHEAD * T_SEQ * HD;   // 4,194,304 floats
    float* q  = (float*)d_ws;
    float* k  = q + TENS;
    float* v  = k + TENS;
    float* ao = v + TENS;

    dim3 g1(M_ROWS / 64, (3 * D_MODEL) / 64);   // 128 x 24
    qkv_gemm<<<g1, 256, 0, stream>>>(x, in_w, in_b, q, k, v);

    // residue-class flash attention: x = tile slot (max 62 used), y = b*H+h
    dim3 g2(64, BATCH * NHEAD);
    attn_rc<<<g2, 256, 0, stream>>>(q, k, v, periods, ao);

    dim3 g3(M_ROWS / 64, D_MODEL / 64);         // 128 x 8
    out_gemm<<<g3, 256, 0, stream>>>(ao, out_w, out_b, out);
}

// Round 4
// 387.168 us; speedup vs baseline: 2.8602x; 1.3082x over previous
//
#include <hip/hip_runtime.h>
#include <math.h>

#define D_MODEL 512
#define NHEAD   8
#define HD      64
#define T_SEQ   2048
#define BATCH   4
#define M_ROWS  (BATCH * T_SEQ)   // 8192

typedef __attribute__((ext_vector_type(8))) short  short8;   // 8 bf16 = 4 VGPRs
typedef __attribute__((ext_vector_type(4))) float  floatx4;

// round-to-nearest-even fp32 -> bf16 (bit math; inputs finite)
__device__ __forceinline__ unsigned short f2bf(float f) {
    unsigned int u = __float_as_uint(f);
    unsigned int r = u + 0x7FFFu + ((u >> 16) & 1u);
    return (unsigned short)(r >> 16);
}

// ---------------------------------------------------------------------------
// fp32 -> bf16 conversion (8 elems/thread, coalesced)
// ---------------------------------------------------------------------------
__global__ __launch_bounds__(256) void cvt_bf16(
    const float* __restrict__ src, unsigned short* __restrict__ dst, int n8)
{
    const int idx = blockIdx.x * 256 + threadIdx.x;
    if (idx >= n8) return;
    const float4 a = ((const float4*)src)[idx * 2];
    const float4 b = ((const float4*)src)[idx * 2 + 1];
    ushort4 lo, hi;
    lo.x = f2bf(a.x); lo.y = f2bf(a.y); lo.z = f2bf(a.z); lo.w = f2bf(a.w);
    hi.x = f2bf(b.x); hi.y = f2bf(b.y); hi.z = f2bf(b.z); hi.w = f2bf(b.w);
    ((ushort4*)dst)[idx * 2]     = lo;
    ((ushort4*)dst)[idx * 2 + 1] = hi;
}

// ---------------------------------------------------------------------------
// Kernel 1: QKV projection, bf16 MFMA.
// C(8192x1536) = Xb(8192x512) @ Wb(1536x512)^T + bias, scattered fp32 into
// head-major q/k/v (B,H,T,64).
// 128x128 block tile, BK=64, 256 threads (4 waves, 2x2 of 64x64 wave-tiles),
// 16x16x32 bf16 MFMA, XOR-swizzled LDS (16B chunk ^= row&7) for conflict-free
// fragment reads.
// ---------------------------------------------------------------------------
__global__ __launch_bounds__(256) void qkv_gemm_mfma(
    const unsigned short* __restrict__ A,   // 8192 x 512 bf16
    const unsigned short* __restrict__ W,   // 1536 x 512 bf16
    const float* __restrict__ bias,
    float* __restrict__ qo, float* __restrict__ ko, float* __restrict__ vo)
{
    __shared__ unsigned short As[128 * 64];
    __shared__ unsigned short Bs[128 * 64];

    const int tid  = threadIdx.x;
    const int wave = tid >> 6, lane = tid & 63;
    const int quad = lane >> 4, l15 = lane & 15;
    const int wm   = wave >> 1, wn = wave & 1;
    const int row0 = blockIdx.x * 128;
    const int col0 = blockIdx.y * 128;
    const int lr8  = lane >> 3;       // staging: row-within-8
    const int sc   = lane & 7;        // staging: 16B chunk 0..7

    floatx4 acc[4][4] = {};

    for (int k0 = 0; k0 < D_MODEL; k0 += 64) {
        int4 av[4], bv[4];
#pragma unroll
        for (int i = 0; i < 4; ++i) {
            const int r = wave * 32 + i * 8 + lr8;
            av[i] = *(const int4*)(A + ((size_t)(row0 + r) << 9) + k0 + (sc << 3));
            bv[i] = *(const int4*)(W + ((size_t)(col0 + r) << 9) + k0 + (sc << 3));
        }
        __syncthreads();
#pragma unroll
        for (int i = 0; i < 4; ++i) {
            const int r  = wave * 32 + i * 8 + lr8;
            const int cp = (sc ^ (r & 7)) << 3;
            *(int4*)(As + (r << 6) + cp) = av[i];
            *(int4*)(Bs + (r << 6) + cp) = bv[i];
        }
        __syncthreads();

#pragma unroll
        for (int ks = 0; ks < 2; ++ks) {
            short8 af[4], bfr[4];
            const int ch = (ks << 2) + quad;
#pragma unroll
            for (int mt = 0; mt < 4; ++mt) {
                const int row = (wm << 6) + (mt << 4) + l15;
                af[mt] = *(const short8*)(As + (row << 6) + ((ch ^ (row & 7)) << 3));
            }
#pragma unroll
            for (int nt = 0; nt < 4; ++nt) {
                const int col = (wn << 6) + (nt << 4) + l15;
                bfr[nt] = *(const short8*)(Bs + (col << 6) + ((ch ^ (col & 7)) << 3));
            }
#pragma unroll
            for (int mt = 0; mt < 4; ++mt)
#pragma unroll
                for (int nt = 0; nt < 4; ++nt)
                    acc[mt][nt] = __builtin_amdgcn_mfma_f32_16x16x32_bf16(
                        af[mt], bfr[nt], acc[mt][nt], 0, 0, 0);
        }
    }

    // epilogue: C row=(quad*4+reg within mt), col=l15 within nt  [m91 layout]
#pragma unroll
    for (int nt = 0; nt < 4; ++nt) {
        const int n    = col0 + (wn << 6) + (nt << 4) + l15;
        const int part = n >> 9;
        float* dst = (part == 0) ? qo : ((part == 1) ? ko : vo);
        const int head = (n & 511) >> 6, d = n & 63;
        const float bn = bias[n];
#pragma unroll
        for (int mt = 0; mt < 4; ++mt) {
#pragma unroll
            for (int reg = 0; reg < 4; ++reg) {
                const int m = row0 + (wm << 6) + (mt << 4) + (quad << 2) + reg;
                const int b = m >> 11, t = m & 2047;
                dst[((((size_t)b << 3) + head) * T_SEQ + t) * HD + d] =
                    acc[mt][nt][reg] + bn;
            }
        }
    }
}

// ---------------------------------------------------------------------------
// Kernel 2: residue-class flash attention (unchanged structure, fp32 math);
// epilogue now writes bf16 head-major for the MFMA out-projection.
// ---------------------------------------------------------------------------
__global__ __launch_bounds__(256) void attn_rc(
    const float* __restrict__ q, const float* __restrict__ k,
    const float* __restrict__ v, const int* __restrict__ periods,
    unsigned short* __restrict__ o)
{
    __shared__ float Qs[64][68];
    __shared__ float KPs[64][68];   // K^T during scores; P̃^T during PV
    __shared__ float Vs[64][68];

    const int bh = blockIdx.y;
    int P = periods[bh]; if (P < 1) P = 1;
    const int q0 = T_SEQ / P, rem = T_SEQ % P;
    const int nt_hi = (q0 + 64) >> 6;
    const int nt_lo = (q0 + 63) >> 6;
    int t = blockIdx.x;
    int r, mt, Lr;
    const int hi_total = rem * nt_hi;
    if (t < hi_total) {
        r = t / nt_hi; mt = t - r * nt_hi; Lr = q0 + 1;
    } else {
        t -= hi_total;
        if (t >= (P - rem) * nt_lo) return;
        const int rr = t / nt_lo;
        r = rem + rr; mt = t - rr * nt_lo; Lr = q0;
    }
    const int m0 = mt << 6;

    const int tid  = threadIdx.x;
    const int tx   = tid & 15, ty = tid >> 4;
    const int srow = tid >> 2;
    const int scol = (tid & 3) << 2;

    const float* hq = q + (size_t)bh * T_SEQ * HD;
    const float* hk = k + (size_t)bh * T_SEQ * HD;
    const float* hv = v + (size_t)bh * T_SEQ * HD;

    {
        int m = m0 + srow; if (m > Lr - 1) m = Lr - 1;
        const float* src = hq + (size_t)(r + m * P) * HD;
#pragma unroll
        for (int rep = 0; rep < 4; ++rep) {
            const int d = scol + (rep << 4);
            float4 a = *(const float4*)(src + d);
            Qs[d+0][srow] = a.x * 0.125f;
            Qs[d+1][srow] = a.y * 0.125f;
            Qs[d+2][srow] = a.z * 0.125f;
            Qs[d+3][srow] = a.w * 0.125f;
        }
    }

    float O[4][4] = {};
    float l_i[4] = {0.f, 0.f, 0.f, 0.f};
    float m_i[4] = {-1e30f, -1e30f, -1e30f, -1e30f};

    for (int kt = 0; kt <= mt; ++kt) {
        const int km0 = kt << 6;

        int mk = km0 + srow; if (mk > Lr - 1) mk = Lr - 1;
        const size_t g = (size_t)(r + mk * P) * HD;
        float4 ka[4], va[4];
#pragma unroll
        for (int rep = 0; rep < 4; ++rep) {
            const int d = scol + (rep << 4);
            ka[rep] = *(const float4*)(hk + g + d);
            va[rep] = *(const float4*)(hv + g + d);
        }
        __syncthreads();
#pragma unroll
        for (int rep = 0; rep < 4; ++rep) {
            const int d = scol + (rep << 4);
            KPs[d+0][srow] = ka[rep].x;
            KPs[d+1][srow] = ka[rep].y;
            KPs[d+2][srow] = ka[rep].z;
            KPs[d+3][srow] = ka[rep].w;
            *(float4*)&Vs[srow][d] = va[rep];
        }
        __syncthreads();

        float acc[4][4] = {};
#pragma unroll 8
        for (int d = 0; d < 64; ++d) {
            float4 qv = *(const float4*)&Qs[d][ty << 2];
            float4 kv = *(const float4*)&KPs[d][tx << 2];
            float qa[4] = {qv.x, qv.y, qv.z, qv.w};
            float kb[4] = {kv.x, kv.y, kv.z, kv.w};
#pragma unroll
            for (int i = 0; i < 4; ++i)
#pragma unroll
                for (int j = 0; j < 4; ++j)
                    acc[i][j] += qa[i] * kb[j];
        }

#pragma unroll
        for (int i = 0; i < 4; ++i) {
            const int sqm = m0 + (ty << 2) + i;
#pragma unroll
            for (int j = 0; j < 4; ++j) {
                const int skm = km0 + (tx << 2) + j;
                if (skm > sqm) acc[i][j] = -1e30f;
            }
        }

        float p[4][4], sc[4];
#pragma unroll
        for (int i = 0; i < 4; ++i) {
            float lm = fmaxf(fmaxf(acc[i][0], acc[i][1]),
                             fmaxf(acc[i][2], acc[i][3]));
            lm = fmaxf(lm, __shfl_xor(lm, 1));
            lm = fmaxf(lm, __shfl_xor(lm, 2));
            lm = fmaxf(lm, __shfl_xor(lm, 4));
            lm = fmaxf(lm, __shfl_xor(lm, 8));
            const float nm = fmaxf(m_i[i], lm);
            sc[i] = __expf(m_i[i] - nm);
            m_i[i] = nm;
            float ps = 0.f;
#pragma unroll
            for (int j = 0; j < 4; ++j) {
                p[i][j] = __expf(acc[i][j] - nm);
                ps += p[i][j];
            }
            ps += __shfl_xor(ps, 1);
            ps += __shfl_xor(ps, 2);
            ps += __shfl_xor(ps, 4);
            ps += __shfl_xor(ps, 8);
            l_i[i] = l_i[i] * sc[i] + ps;
        }

        __syncthreads();
#pragma unroll
        for (int j = 0; j < 4; ++j)
#pragma unroll
            for (int i = 0; i < 4; ++i)
                KPs[(tx << 2) + j][(ty << 2) + i] = p[i][j];
        __syncthreads();

#pragma unroll
        for (int i = 0; i < 4; ++i)
#pragma unroll
            for (int j = 0; j < 4; ++j)
                O[i][j] *= sc[i];

#pragma unroll 4
        for (int km = 0; km < 64; ++km) {
            float4 pv = *(const float4*)&KPs[km][ty << 2];
            float4 vv = *(const float4*)&Vs[km][tx << 2];
            float pa[4] = {pv.x, pv.y, pv.z, pv.w};
            float vb[4] = {vv.x, vv.y, vv.z, vv.w};
#pragma unroll
            for (int i = 0; i < 4; ++i)
#pragma unroll
                for (int j = 0; j < 4; ++j)
                    O[i][j] += pa[i] * vb[j];
        }
    }

#pragma unroll
    for (int i = 0; i < 4; ++i) {
        const int m = m0 + (ty << 2) + i;
        if (m < Lr) {
            const float inv = 1.f / l_i[i];
            ushort4 s;
            s.x = f2bf(O[i][0] * inv);
            s.y = f2bf(O[i][1] * inv);
            s.z = f2bf(O[i][2] * inv);
            s.w = f2bf(O[i][3] * inv);
            *(ushort4*)&o[((size_t)bh * T_SEQ + (r + m * P)) * HD + (tx << 2)] = s;
        }
    }
}

// ---------------------------------------------------------------------------
// Kernel 3: out projection, bf16 MFMA.
// out(8192x512) = Ab @ Wob^T + out_b, where Ab is head-major (B,H,T,64) bf16.
// BK=64 slabs align exactly with heads: slab k0 -> head h = k0>>6.
// ---------------------------------------------------------------------------
__global__ __launch_bounds__(256) void out_gemm_mfma(
    const unsigned short* __restrict__ A,   // (B,H,T,64) bf16
    const unsigned short* __restrict__ W,   // 512 x 512 bf16
    const float* __restrict__ bias,
    float* __restrict__ out)
{
    __shared__ unsigned short As[128 * 64];
    __shared__ unsigned short Bs[128 * 64];

    const int tid  = threadIdx.x;
    const int wave = tid >> 6, lane = tid & 63;
    const int quad = lane >> 4, l15 = lane & 15;
    const int wm   = wave >> 1, wn = wave & 1;
    const int row0 = blockIdx.x * 128;
    const int col0 = blockIdx.y * 128;
    const int lr8  = lane >> 3;
    const int sc   = lane & 7;

    floatx4 acc[4][4] = {};

    for (int k0 = 0; k0 < D_MODEL; k0 += 64) {
        const int h = k0 >> 6;
        int4 av[4], bv[4];
#pragma unroll
        for (int i = 0; i < 4; ++i) {
            const int r  = wave * 32 + i * 8 + lr8;
            const int rg = row0 + r;
            const int b = rg >> 11, t = rg & 2047;
            av[i] = *(const int4*)(A + ((((size_t)b << 3) + h) * T_SEQ + t) * HD + (sc << 3));
            bv[i] = *(const int4*)(W + ((size_t)(col0 + r) << 9) + k0 + (sc << 3));
        }
        __syncthreads();
#pragma unroll
        for (int i = 0; i < 4; ++i) {
            const int r  = wave * 32 + i * 8 + lr8;
            const int cp = (sc ^ (r & 7)) << 3;
            *(int4*)(As + (r << 6) + cp) = av[i];
            *(int4*)(Bs + (r << 6) + cp) = bv[i];
        }
        __syncthreads();

#pragma unroll
        for (int ks = 0; ks < 2; ++ks) {
            short8 af[4], bfr[4];
            const int ch = (ks << 2) + quad;
#pragma unroll
            for (int mt = 0; mt < 4; ++mt) {
                const int row = (wm << 6) + (mt << 4) + l15;
                af[mt] = *(const short8*)(As + (row << 6) + ((ch ^ (row & 7)) << 3));
            }
#pragma unroll
            for (int nt = 0; nt < 4; ++nt) {
                const int col = (wn << 6) + (nt << 4) + l15;
                bfr[nt] = *(const short8*)(Bs + (col << 6) + ((ch ^ (col & 7)) << 3));
            }
#pragma unroll
            for (int mt = 0; mt < 4; ++mt)
#pragma unroll
                for (int nt = 0; nt < 4; ++nt)
                    acc[mt][nt] = __builtin_amdgcn_mfma_f32_16x16x32_bf16(
                        af[mt], bfr[nt], acc[mt][nt], 0, 0, 0);
        }
    }

#pragma unroll
    for (int nt = 0; nt < 4; ++nt) {
        const int n = col0 + (wn << 6) + (nt << 4) + l15;
        const float bn = bias[n];
#pragma unroll
        for (int mt = 0; mt < 4; ++mt) {
#pragma unroll
            for (int reg = 0; reg < 4; ++reg) {
                const int m = row0 + (wm << 6) + (mt << 4) + (quad << 2) + reg;
                out[(size_t)m * D_MODEL + n] = acc[mt][nt][reg] + bn;
            }
        }
    }
}

// ---------------------------------------------------------------------------
extern "C" void kernel_launch(void* const* d_in, const int* in_sizes, int n_in,
                              void* d_out, int out_size, void* d_ws, size_t ws_size,
                              hipStream_t stream)
{
    const float* x        = (const float*)d_in[0];
    const int*   periods  = (const int*)  d_in[1];
    const float* in_w     = (const float*)d_in[2];
    const float* in_b     = (const float*)d_in[3];
    const float* out_w    = (const float*)d_in[4];
    const float* out_b    = (const float*)d_in[5];
    float*       out      = (float*)d_out;

    const size_t TENS = (size_t)BATCH * NHEAD * T_SEQ * HD;   // 4,194,304
    float* q = (float*)d_ws;
    float* k = q + TENS;
    float* v = k + TENS;
    unsigned short* xb    = (unsigned short*)(v + TENS);      // x in bf16
    unsigned short* aob   = xb;                               // alias: xb dead after qkv_gemm
    unsigned short* wqkvb = xb + TENS;                        // 786,432
    unsigned short* wob   = wqkvb + (size_t)3 * D_MODEL * D_MODEL; // 262,144
    // total ws: 50.3 MB fp32 + 10.5 MB bf16 = 60.8 MB

    // 0) fp32 -> bf16 conversions
    cvt_bf16<<<(int)(TENS / 8 / 256), 256, 0, stream>>>(x, xb, (int)(TENS / 8));
    cvt_bf16<<<(3 * D_MODEL * D_MODEL / 8) / 256, 256, 0, stream>>>(in_w, wqkvb, 3 * D_MODEL * D_MODEL / 8);
    cvt_bf16<<<(D_MODEL * D_MODEL / 8) / 256, 256, 0, stream>>>(out_w, wob, D_MODEL * D_MODEL / 8);

    // 1) QKV projection (bf16 MFMA) -> head-major fp32 q,k,v
    dim3 g1(M_ROWS / 128, (3 * D_MODEL) / 128);   // 64 x 12
    qkv_gemm_mfma<<<g1, 256, 0, stream>>>(xb, wqkvb, in_b, q, k, v);

    // 2) residue-class flash attention -> bf16 head-major
    dim3 g2(64, BATCH * NHEAD);
    attn_rc<<<g2, 256, 0, stream>>>(q, k, v, periods, aob);

    // 3) out projection (bf16 MFMA)
    dim3 g3(M_ROWS / 128, D_MODEL / 128);         // 64 x 4
    out_gemm_mfma<<<g3, 256, 0, stream>>>(aob, wob, out_b, out);
}

// Round 5
// 242.051 us; speedup vs baseline: 4.5749x; 1.5995x over previous
//
#include <hip/hip_runtime.h>
#include <math.h>

#define D_MODEL 512
#define NHEAD   8
#define HD      64
#define T_SEQ   2048
#define BATCH   4
#define M_ROWS  (BATCH * T_SEQ)   // 8192

typedef __attribute__((ext_vector_type(8))) short  short8;   // 8 bf16 = 4 VGPRs
typedef __attribute__((ext_vector_type(4))) float  floatx4;

// round-to-nearest-even fp32 -> bf16 (bit math; inputs finite)
__device__ __forceinline__ unsigned short f2bf(float f) {
    unsigned int u = __float_as_uint(f);
    unsigned int r = u + 0x7FFFu + ((u >> 16) & 1u);
    return (unsigned short)(r >> 16);
}

// ---------------------------------------------------------------------------
// fp32 -> bf16 conversion (8 elems/thread, coalesced)
// ---------------------------------------------------------------------------
__global__ __launch_bounds__(256) void cvt_bf16(
    const float* __restrict__ src, unsigned short* __restrict__ dst, int n8)
{
    const int idx = blockIdx.x * 256 + threadIdx.x;
    if (idx >= n8) return;
    const float4 a = ((const float4*)src)[idx * 2];
    const float4 b = ((const float4*)src)[idx * 2 + 1];
    ushort4 lo, hi;
    lo.x = f2bf(a.x); lo.y = f2bf(a.y); lo.z = f2bf(a.z); lo.w = f2bf(a.w);
    hi.x = f2bf(b.x); hi.y = f2bf(b.y); hi.z = f2bf(b.z); hi.w = f2bf(b.w);
    ((ushort4*)dst)[idx * 2]     = lo;
    ((ushort4*)dst)[idx * 2 + 1] = hi;
}

// ---------------------------------------------------------------------------
// Kernel 1: QKV projection, bf16 MFMA; emits q/k/v as bf16 head-major.
// ---------------------------------------------------------------------------
__global__ __launch_bounds__(256) void qkv_gemm_mfma(
    const unsigned short* __restrict__ A,   // 8192 x 512 bf16
    const unsigned short* __restrict__ W,   // 1536 x 512 bf16
    const float* __restrict__ bias,
    unsigned short* __restrict__ qo, unsigned short* __restrict__ ko,
    unsigned short* __restrict__ vo)
{
    __shared__ unsigned short As[128 * 64];
    __shared__ unsigned short Bs[128 * 64];

    const int tid  = threadIdx.x;
    const int wave = tid >> 6, lane = tid & 63;
    const int quad = lane >> 4, l15 = lane & 15;
    const int wm   = wave >> 1, wn = wave & 1;
    const int row0 = blockIdx.x * 128;
    const int col0 = blockIdx.y * 128;
    const int lr8  = lane >> 3;       // staging: row-within-8
    const int sc   = lane & 7;        // staging: 16B chunk 0..7

    floatx4 acc[4][4] = {};

    for (int k0 = 0; k0 < D_MODEL; k0 += 64) {
        int4 av[4], bv[4];
#pragma unroll
        for (int i = 0; i < 4; ++i) {
            const int r = wave * 32 + i * 8 + lr8;
            av[i] = *(const int4*)(A + ((size_t)(row0 + r) << 9) + k0 + (sc << 3));
            bv[i] = *(const int4*)(W + ((size_t)(col0 + r) << 9) + k0 + (sc << 3));
        }
        __syncthreads();
#pragma unroll
        for (int i = 0; i < 4; ++i) {
            const int r  = wave * 32 + i * 8 + lr8;
            const int cp = (sc ^ (r & 7)) << 3;
            *(int4*)(As + (r << 6) + cp) = av[i];
            *(int4*)(Bs + (r << 6) + cp) = bv[i];
        }
        __syncthreads();

#pragma unroll
        for (int ks = 0; ks < 2; ++ks) {
            short8 af[4], bfr[4];
            const int ch = (ks << 2) + quad;
#pragma unroll
            for (int mt = 0; mt < 4; ++mt) {
                const int row = (wm << 6) + (mt << 4) + l15;
                af[mt] = *(const short8*)(As + (row << 6) + ((ch ^ (row & 7)) << 3));
            }
#pragma unroll
            for (int nt = 0; nt < 4; ++nt) {
                const int col = (wn << 6) + (nt << 4) + l15;
                bfr[nt] = *(const short8*)(Bs + (col << 6) + ((ch ^ (col & 7)) << 3));
            }
#pragma unroll
            for (int mt = 0; mt < 4; ++mt)
#pragma unroll
                for (int nt = 0; nt < 4; ++nt)
                    acc[mt][nt] = __builtin_amdgcn_mfma_f32_16x16x32_bf16(
                        af[mt], bfr[nt], acc[mt][nt], 0, 0, 0);
        }
    }

    // epilogue: C row=quad*4+reg, col=l15  [m91 layout] -> bf16 head-major
#pragma unroll
    for (int nt = 0; nt < 4; ++nt) {
        const int n    = col0 + (wn << 6) + (nt << 4) + l15;
        const int part = n >> 9;
        unsigned short* dst = (part == 0) ? qo : ((part == 1) ? ko : vo);
        const int head = (n & 511) >> 6, d = n & 63;
        const float bn = bias[n];
#pragma unroll
        for (int mt = 0; mt < 4; ++mt) {
#pragma unroll
            for (int reg = 0; reg < 4; ++reg) {
                const int m = row0 + (wm << 6) + (mt << 4) + (quad << 2) + reg;
                const int b = m >> 11, t = m & 2047;
                dst[((((size_t)b << 3) + head) * T_SEQ + t) * HD + d] =
                    f2bf(acc[mt][nt][reg] + bn);
            }
        }
    }
}

// ---------------------------------------------------------------------------
// Kernel 2: residue-class flash attention with bf16 MFMA.
// Block = (bh, residue r, 64-query tile mt), 256 threads = 4 waves.
// Wave w owns local query rows w*16..w*16+15.
// Per 64-key tile: QK^T = 8 MFMA/wave, online softmax on fp32 C-regs,
// P̃ -> LDS (bf16, A-layout via round-trip), PV = 8 MFMA/wave.
// LDS tiles 64x64 bf16, XOR chunk swizzle (^row&7), stride 64.
// ---------------------------------------------------------------------------
__global__ __launch_bounds__(256) void attn_rc_mfma(
    const unsigned short* __restrict__ q, const unsigned short* __restrict__ k,
    const unsigned short* __restrict__ v, const int* __restrict__ periods,
    unsigned short* __restrict__ o)
{
    __shared__ unsigned short Ks[64 * 64];   // [key][hd]
    __shared__ unsigned short Vt[64 * 64];   // [hd][key]
    __shared__ unsigned short Ps[64 * 64];   // Q tile, then P̃ [q][key]

    const int bh = blockIdx.y;
    int P = periods[bh]; if (P < 1) P = 1;
    const int q0 = T_SEQ / P, rem = T_SEQ % P;
    const int nt_hi = (q0 + 64) >> 6;
    const int nt_lo = (q0 + 63) >> 6;
    int t = blockIdx.x;
    int r, mt, Lr;
    const int hi_total = rem * nt_hi;
    if (t < hi_total) {
        r = t / nt_hi; mt = t - r * nt_hi; Lr = q0 + 1;
    } else {
        t -= hi_total;
        if (t >= (P - rem) * nt_lo) return;
        const int rr = t / nt_lo;
        r = rem + rr; mt = t - rr * nt_lo; Lr = q0;
    }
    const int m0 = mt << 6;

    const int tid  = threadIdx.x;
    const int wave = tid >> 6, lane = tid & 63;
    const int quad = lane >> 4, l15 = lane & 15;
    const int srow = tid >> 2;                 // K/Q staging row 0..63
    const int vkp  = tid & 31, vhg = tid >> 5; // V staging: keys 2vkp,2vkp+1; hds vhg*8..+7

    const unsigned short* hq = q + (size_t)bh * T_SEQ * HD;
    const unsigned short* hk = k + (size_t)bh * T_SEQ * HD;
    const unsigned short* hv = v + (size_t)bh * T_SEQ * HD;

    // ---- stage Q tile into Ps, pull A-frags to regs ----
    {
        int m = m0 + srow; if (m > Lr - 1) m = Lr - 1;
        const unsigned short* src = hq + (size_t)(r + m * P) * HD;
#pragma unroll
        for (int rep = 0; rep < 2; ++rep) {
            const int c = ((tid & 3) << 1) + rep;
            int4 a = *(const int4*)(src + (c << 3));
            *(int4*)(Ps + (srow << 6) + ((c ^ (srow & 7)) << 3)) = a;
        }
    }
    __syncthreads();
    short8 qf[2];
#pragma unroll
    for (int ks = 0; ks < 2; ++ks) {
        const int row = (wave << 4) + l15;
        qf[ks] = *(const short8*)(Ps + (row << 6) +
                                  ((((ks << 2) + quad) ^ (row & 7)) << 3));
    }
    // Ps reused for P̃ below: each wave writes/reads only its own 16 rows,
    // and DS ops complete in order within a wave -> no extra barrier needed.

    floatx4 Oa[4] = {};                        // O[hd-tile][reg], C-layout
    float m_i[4] = {-1e30f, -1e30f, -1e30f, -1e30f};
    float l_i[4] = {0.f, 0.f, 0.f, 0.f};

    for (int kt = 0; kt <= mt; ++kt) {
        const int km0 = kt << 6;

        // ---- global loads (issued before the barrier) ----
        int mk = km0 + srow; if (mk > Lr - 1) mk = Lr - 1;
        const unsigned short* ksrc = hk + (size_t)(r + mk * P) * HD;
        int4 ka[2];
#pragma unroll
        for (int rep = 0; rep < 2; ++rep)
            ka[rep] = *(const int4*)(ksrc + ((((tid & 3) << 1) + rep) << 3));
        int mv0 = km0 + (vkp << 1);     if (mv0 > Lr - 1) mv0 = Lr - 1;
        int mv1 = km0 + (vkp << 1) + 1; if (mv1 > Lr - 1) mv1 = Lr - 1;
        int4 va = *(const int4*)(hv + (size_t)(r + mv0 * P) * HD + (vhg << 3));
        int4 vb = *(const int4*)(hv + (size_t)(r + mv1 * P) * HD + (vhg << 3));

        __syncthreads();   // previous iteration's fragment reads complete

        // K [key][hd] row-major, swizzled
#pragma unroll
        for (int rep = 0; rep < 2; ++rep) {
            const int c = ((tid & 3) << 1) + rep;
            *(int4*)(Ks + (srow << 6) + ((c ^ (srow & 7)) << 3)) = ka[rep];
        }
        // V transpose -> Vt [hd][key]: pack key-pair into b32
        {
            const unsigned short* pa = (const unsigned short*)&va;
            const unsigned short* pb = (const unsigned short*)&vb;
#pragma unroll
            for (int j = 0; j < 8; ++j) {
                const int hd_ = (vhg << 3) + j;
                const unsigned int pk =
                    (unsigned int)pa[j] | ((unsigned int)pb[j] << 16);
                *(unsigned int*)((char*)Vt + (hd_ << 7) +
                                 ((((vkp >> 2) ^ (hd_ & 7)) << 4)) +
                                 ((vkp & 3) << 2)) = pk;
            }
        }
        __syncthreads();

        // ---- QK^T: C[q=quad*4+reg (+w*16)][key=nt*16+l15] ----
        floatx4 sacc[4] = {};
#pragma unroll
        for (int nt = 0; nt < 4; ++nt) {
            const int row = (nt << 4) + l15;
#pragma unroll
            for (int ks = 0; ks < 2; ++ks) {
                short8 kf = *(const short8*)(Ks + (row << 6) +
                                             ((((ks << 2) + quad) ^ (row & 7)) << 3));
                sacc[nt] = __builtin_amdgcn_mfma_f32_16x16x32_bf16(
                    qf[ks], kf, sacc[nt], 0, 0, 0);
            }
        }

        // ---- scale + causal mask (diagonal tile only) + online softmax ----
        const bool diag = (kt == mt);
        float p[4][4], sc[4];
#pragma unroll
        for (int reg = 0; reg < 4; ++reg) {
            float s[4];
#pragma unroll
            for (int nt = 0; nt < 4; ++nt) s[nt] = sacc[nt][reg] * 0.125f;
            if (diag) {
                const int sq = (wave << 4) + (quad << 2) + reg;  // local q idx
#pragma unroll
                for (int nt = 0; nt < 4; ++nt)
                    if (((nt << 4) + l15) > sq) s[nt] = -1e30f;
            }
            float rm = fmaxf(fmaxf(s[0], s[1]), fmaxf(s[2], s[3]));
            rm = fmaxf(rm, __shfl_xor(rm, 1));
            rm = fmaxf(rm, __shfl_xor(rm, 2));
            rm = fmaxf(rm, __shfl_xor(rm, 4));
            rm = fmaxf(rm, __shfl_xor(rm, 8));
            const float nm = fmaxf(m_i[reg], rm);
            sc[reg] = __expf(m_i[reg] - nm);
            m_i[reg] = nm;
            float ps = 0.f;
#pragma unroll
            for (int nt = 0; nt < 4; ++nt) {
                p[nt][reg] = __expf(s[nt] - nm);
                ps += p[nt][reg];
            }
            ps += __shfl_xor(ps, 1);
            ps += __shfl_xor(ps, 2);
            ps += __shfl_xor(ps, 4);
            ps += __shfl_xor(ps, 8);
            l_i[reg] = l_i[reg] * sc[reg] + ps;
        }

        // ---- P̃ -> Ps [q][key] bf16 (own-wave rows only) ----
#pragma unroll
        for (int reg = 0; reg < 4; ++reg) {
            const int row = (wave << 4) + (quad << 2) + reg;
#pragma unroll
            for (int nt = 0; nt < 4; ++nt) {
                const int col = (nt << 4) + l15;
                *((unsigned short*)((char*)Ps + (row << 7) +
                                    (((col >> 3) ^ (row & 7)) << 4) +
                                    ((col & 7) << 1))) = f2bf(p[nt][reg]);
            }
        }

        // ---- PV: O[q][hd=nt*16+l15] += P̃ · V ----
        short8 pf[2];
#pragma unroll
        for (int ks = 0; ks < 2; ++ks) {
            const int row = (wave << 4) + l15;
            pf[ks] = *(const short8*)(Ps + (row << 6) +
                                      ((((ks << 2) + quad) ^ (row & 7)) << 3));
        }
#pragma unroll
        for (int nt = 0; nt < 4; ++nt)
#pragma unroll
            for (int reg = 0; reg < 4; ++reg)
                Oa[nt][reg] *= sc[reg];
#pragma unroll
        for (int nt = 0; nt < 4; ++nt) {
            const int row = (nt << 4) + l15;
#pragma unroll
            for (int ks = 0; ks < 2; ++ks) {
                short8 vf = *(const short8*)(Vt + (row << 6) +
                                             ((((ks << 2) + quad) ^ (row & 7)) << 3));
                Oa[nt] = __builtin_amdgcn_mfma_f32_16x16x32_bf16(
                    pf[ks], vf, Oa[nt], 0, 0, 0);
            }
        }
    }

    // ---- store valid rows as bf16 head-major ----
#pragma unroll
    for (int reg = 0; reg < 4; ++reg) {
        const int ml = (wave << 4) + (quad << 2) + reg;
        const int m  = m0 + ml;
        if (m < Lr) {
            const float invl = 1.f / l_i[reg];
            const size_t base = ((size_t)bh * T_SEQ + (r + m * P)) * HD;
#pragma unroll
            for (int nt = 0; nt < 4; ++nt)
                o[base + (nt << 4) + l15] = f2bf(Oa[nt][reg] * invl);
        }
    }
}

// ---------------------------------------------------------------------------
// Kernel 3: out projection, bf16 MFMA (A head-major (B,H,T,64) bf16).
// ---------------------------------------------------------------------------
__global__ __launch_bounds__(256) void out_gemm_mfma(
    const unsigned short* __restrict__ A,
    const unsigned short* __restrict__ W,   // 512 x 512 bf16
    const float* __restrict__ bias,
    float* __restrict__ out)
{
    __shared__ unsigned short As[128 * 64];
    __shared__ unsigned short Bs[128 * 64];

    const int tid  = threadIdx.x;
    const int wave = tid >> 6, lane = tid & 63;
    const int quad = lane >> 4, l15 = lane & 15;
    const int wm   = wave >> 1, wn = wave & 1;
    const int row0 = blockIdx.x * 128;
    const int col0 = blockIdx.y * 128;
    const int lr8  = lane >> 3;
    const int sc   = lane & 7;

    floatx4 acc[4][4] = {};

    for (int k0 = 0; k0 < D_MODEL; k0 += 64) {
        const int h = k0 >> 6;
        int4 av[4], bv[4];
#pragma unroll
        for (int i = 0; i < 4; ++i) {
            const int r  = wave * 32 + i * 8 + lr8;
            const int rg = row0 + r;
            const int b = rg >> 11, t = rg & 2047;
            av[i] = *(const int4*)(A + ((((size_t)b << 3) + h) * T_SEQ + t) * HD + (sc << 3));
            bv[i] = *(const int4*)(W + ((size_t)(col0 + r) << 9) + k0 + (sc << 3));
        }
        __syncthreads();
#pragma unroll
        for (int i = 0; i < 4; ++i) {
            const int r  = wave * 32 + i * 8 + lr8;
            const int cp = (sc ^ (r & 7)) << 3;
            *(int4*)(As + (r << 6) + cp) = av[i];
            *(int4*)(Bs + (r << 6) + cp) = bv[i];
        }
        __syncthreads();

#pragma unroll
        for (int ks = 0; ks < 2; ++ks) {
            short8 af[4], bfr[4];
            const int ch = (ks << 2) + quad;
#pragma unroll
            for (int mt = 0; mt < 4; ++mt) {
                const int row = (wm << 6) + (mt << 4) + l15;
                af[mt] = *(const short8*)(As + (row << 6) + ((ch ^ (row & 7)) << 3));
            }
#pragma unroll
            for (int nt = 0; nt < 4; ++nt) {
                const int col = (wn << 6) + (nt << 4) + l15;
                bfr[nt] = *(const short8*)(Bs + (col << 6) + ((ch ^ (col & 7)) << 3));
            }
#pragma unroll
            for (int mt = 0; mt < 4; ++mt)
#pragma unroll
                for (int nt = 0; nt < 4; ++nt)
                    acc[mt][nt] = __builtin_amdgcn_mfma_f32_16x16x32_bf16(
                        af[mt], bfr[nt], acc[mt][nt], 0, 0, 0);
        }
    }

#pragma unroll
    for (int nt = 0; nt < 4; ++nt) {
        const int n = col0 + (wn << 6) + (nt << 4) + l15;
        const float bn = bias[n];
#pragma unroll
        for (int mt = 0; mt < 4; ++mt) {
#pragma unroll
            for (int reg = 0; reg < 4; ++reg) {
                const int m = row0 + (wm << 6) + (mt << 4) + (quad << 2) + reg;
                out[(size_t)m * D_MODEL + n] = acc[mt][nt][reg] + bn;
            }
        }
    }
}

// ---------------------------------------------------------------------------
extern "C" void kernel_launch(void* const* d_in, const int* in_sizes, int n_in,
                              void* d_out, int out_size, void* d_ws, size_t ws_size,
                              hipStream_t stream)
{
    const float* x        = (const float*)d_in[0];
    const int*   periods  = (const int*)  d_in[1];
    const float* in_w     = (const float*)d_in[2];
    const float* in_b     = (const float*)d_in[3];
    const float* out_w    = (const float*)d_in[4];
    const float* out_b    = (const float*)d_in[5];
    float*       out      = (float*)d_out;

    const size_t TENS = (size_t)BATCH * NHEAD * T_SEQ * HD;   // 4,194,304
    unsigned short* qb    = (unsigned short*)d_ws;
    unsigned short* kb    = qb + TENS;
    unsigned short* vb    = kb + TENS;
    unsigned short* xb    = vb + TENS;
    unsigned short* wqkvb = xb + TENS;
    unsigned short* wob   = wqkvb + (size_t)3 * D_MODEL * D_MODEL;
    unsigned short* aob   = xb;   // alias: xb dead after qkv_gemm
    // ws: 5*TENS + 4*512*512 shorts ~= 44 MB

    // 0) fp32 -> bf16 conversions
    cvt_bf16<<<(int)(TENS / 8 / 256), 256, 0, stream>>>(x, xb, (int)(TENS / 8));
    cvt_bf16<<<(3 * D_MODEL * D_MODEL / 8) / 256, 256, 0, stream>>>(in_w, wqkvb, 3 * D_MODEL * D_MODEL / 8);
    cvt_bf16<<<(D_MODEL * D_MODEL / 8) / 256, 256, 0, stream>>>(out_w, wob, D_MODEL * D_MODEL / 8);

    // 1) QKV projection (bf16 MFMA) -> bf16 head-major q,k,v
    dim3 g1(M_ROWS / 128, (3 * D_MODEL) / 128);   // 64 x 12
    qkv_gemm_mfma<<<g1, 256, 0, stream>>>(xb, wqkvb, in_b, qb, kb, vb);

    // 2) residue-class flash attention (MFMA) -> bf16 head-major
    dim3 g2(64, BATCH * NHEAD);
    attn_rc_mfma<<<g2, 256, 0, stream>>>(qb, kb, vb, periods, aob);

    // 3) out projection (bf16 MFMA)
    dim3 g3(M_ROWS / 128, D_MODEL / 128);         // 64 x 4
    out_gemm_mfma<<<g3, 256, 0, stream>>>(aob, wob, out_b, out);
}

// Round 6
// 240.788 us; speedup vs baseline: 4.5989x; 1.0052x over previous
//
#include <hip/hip_runtime.h>
#include <math.h>

#define D_MODEL 512
#define NHEAD   8
#define HD      64
#define T_SEQ   2048
#define BATCH   4
#define M_ROWS  (BATCH * T_SEQ)   // 8192

typedef __attribute__((ext_vector_type(8))) short  short8;   // 8 bf16 = 4 VGPRs
typedef __attribute__((ext_vector_type(4))) float  floatx4;

// round-to-nearest-even fp32 -> bf16 (bit math; inputs finite)
__device__ __forceinline__ unsigned short f2bf(float f) {
    unsigned int u = __float_as_uint(f);
    unsigned int r = u + 0x7FFFu + ((u >> 16) & 1u);
    return (unsigned short)(r >> 16);
}

// ---------------------------------------------------------------------------
// fp32 -> bf16 conversion (8 elems/thread, coalesced)
// ---------------------------------------------------------------------------
__global__ __launch_bounds__(256) void cvt_bf16(
    const float* __restrict__ src, unsigned short* __restrict__ dst, int n8)
{
    const int idx = blockIdx.x * 256 + threadIdx.x;
    if (idx >= n8) return;
    const float4 a = ((const float4*)src)[idx * 2];
    const float4 b = ((const float4*)src)[idx * 2 + 1];
    ushort4 lo, hi;
    lo.x = f2bf(a.x); lo.y = f2bf(a.y); lo.z = f2bf(a.z); lo.w = f2bf(a.w);
    hi.x = f2bf(b.x); hi.y = f2bf(b.y); hi.z = f2bf(b.z); hi.w = f2bf(b.w);
    ((ushort4*)dst)[idx * 2]     = lo;
    ((ushort4*)dst)[idx * 2 + 1] = hi;
}

// ---------------------------------------------------------------------------
// Kernel 1: QKV projection, bf16 MFMA; emits q/k/v as bf16 head-major.
// Epilogue transposes through LDS so every global store writes full 128-B
// lines (fix for the 4.7x WRITE amplification seen with 2-B scalar stores).
// Grid is flat 768 with an XCD-aware swizzle: XCD x handles row-tiles
// {x, 8+x, ...} for all 12 col-tiles -> A slabs stay L2-resident.
// ---------------------------------------------------------------------------
__global__ __launch_bounds__(256) void qkv_gemm_mfma(
    const unsigned short* __restrict__ A,   // 8192 x 512 bf16
    const unsigned short* __restrict__ W,   // 1536 x 512 bf16
    const float* __restrict__ bias,
    unsigned short* __restrict__ qo, unsigned short* __restrict__ ko,
    unsigned short* __restrict__ vo)
{
    __shared__ unsigned short smem[128 * 128];    // 32 KB: As|Bs, then C-tile
    unsigned short* const As = smem;              // 128 x 64
    unsigned short* const Bs = smem + 128 * 64;   // 128 x 64

    const int bid  = blockIdx.x;
    const int xcd  = bid & 7;
    const int chk_ = bid >> 3;                            // 0..95
    const int row0 = (((chk_ / 12) << 3) + xcd) << 7;     // row-tile * 128
    const int col0 = (chk_ % 12) << 7;                    // col-tile * 128

    const int tid  = threadIdx.x;
    const int wave = tid >> 6, lane = tid & 63;
    const int quad = lane >> 4, l15 = lane & 15;
    const int wm   = wave >> 1, wn = wave & 1;
    const int lr8  = lane >> 3;       // staging: row-within-8
    const int sc   = lane & 7;        // staging: 16B chunk 0..7

    floatx4 acc[4][4] = {};

    for (int k0 = 0; k0 < D_MODEL; k0 += 64) {
        int4 av[4], bv[4];
#pragma unroll
        for (int i = 0; i < 4; ++i) {
            const int r = wave * 32 + i * 8 + lr8;
            av[i] = *(const int4*)(A + ((size_t)(row0 + r) << 9) + k0 + (sc << 3));
            bv[i] = *(const int4*)(W + ((size_t)(col0 + r) << 9) + k0 + (sc << 3));
        }
        __syncthreads();
#pragma unroll
        for (int i = 0; i < 4; ++i) {
            const int r  = wave * 32 + i * 8 + lr8;
            const int cp = (sc ^ (r & 7)) << 3;
            *(int4*)(As + (r << 6) + cp) = av[i];
            *(int4*)(Bs + (r << 6) + cp) = bv[i];
        }
        __syncthreads();

#pragma unroll
        for (int ks = 0; ks < 2; ++ks) {
            short8 af[4], bfr[4];
            const int ch = (ks << 2) + quad;
#pragma unroll
            for (int mt = 0; mt < 4; ++mt) {
                const int row = (wm << 6) + (mt << 4) + l15;
                af[mt] = *(const short8*)(As + (row << 6) + ((ch ^ (row & 7)) << 3));
            }
#pragma unroll
            for (int nt = 0; nt < 4; ++nt) {
                const int col = (wn << 6) + (nt << 4) + l15;
                bfr[nt] = *(const short8*)(Bs + (col << 6) + ((ch ^ (col & 7)) << 3));
            }
#pragma unroll
            for (int mt = 0; mt < 4; ++mt)
#pragma unroll
                for (int nt = 0; nt < 4; ++nt)
                    acc[mt][nt] = __builtin_amdgcn_mfma_f32_16x16x32_bf16(
                        af[mt], bfr[nt], acc[mt][nt], 0, 0, 0);
        }
    }

    // ---- epilogue: bias + bf16 -> LDS 128x128, then full-line stores ----
    __syncthreads();          // all waves done with As/Bs fragments
#pragma unroll
    for (int nt = 0; nt < 4; ++nt) {
        const int ncol = (wn << 6) + (nt << 4) + l15;
        const float bn = bias[col0 + ncol];
#pragma unroll
        for (int mt = 0; mt < 4; ++mt)
#pragma unroll
            for (int reg = 0; reg < 4; ++reg) {
                const int mrow = (wm << 6) + (mt << 4) + (quad << 2) + reg;
                smem[(mrow << 7) + ncol] = f2bf(acc[mt][nt][reg] + bn);
            }
    }
    __syncthreads();
    {
        const int c16  = lane & 15;            // 16-B chunk 0..15 (128 cols)
        const int rsub = lane >> 4;            // row-within-4
        const int n0   = col0 + (c16 << 3);
        const int part = n0 >> 9;
        unsigned short* dst = (part == 0) ? qo : ((part == 1) ? ko : vo);
        const int head = (n0 & 511) >> 6, d0 = n0 & 63;
#pragma unroll
        for (int p = 0; p < 8; ++p) {
            const int ml = (wave << 5) + (p << 2) + rsub;   // 0..127
            const int m  = row0 + ml;
            const int b = m >> 11, t = m & 2047;
            int4 val = *(const int4*)(smem + (ml << 7) + (c16 << 3));
            *(int4*)(dst + ((((size_t)b << 3) + head) * T_SEQ + t) * HD + d0) = val;
        }
    }
}

// ---------------------------------------------------------------------------
// Kernel 2: residue-class flash attention with bf16 MFMA.
// Epilogue now round-trips O through LDS (dead Ks buffer) so each t-row is
// written as one full 128-B line instead of 2-B scalar fragments.
// ---------------------------------------------------------------------------
__global__ __launch_bounds__(256) void attn_rc_mfma(
    const unsigned short* __restrict__ q, const unsigned short* __restrict__ k,
    const unsigned short* __restrict__ v, const int* __restrict__ periods,
    unsigned short* __restrict__ o)
{
    __shared__ unsigned short Ks[64 * 64];   // [key][hd]; O-tile in epilogue
    __shared__ unsigned short Vt[64 * 64];   // [hd][key]
    __shared__ unsigned short Ps[64 * 64];   // Q tile, then P̃ [q][key]

    const int bh = blockIdx.y;
    int P = periods[bh]; if (P < 1) P = 1;
    const int q0 = T_SEQ / P, rem = T_SEQ % P;
    const int nt_hi = (q0 + 64) >> 6;
    const int nt_lo = (q0 + 63) >> 6;
    int t = blockIdx.x;
    int r, mt, Lr;
    const int hi_total = rem * nt_hi;
    if (t < hi_total) {
        r = t / nt_hi; mt = t - r * nt_hi; Lr = q0 + 1;
    } else {
        t -= hi_total;
        if (t >= (P - rem) * nt_lo) return;
        const int rr = t / nt_lo;
        r = rem + rr; mt = t - rr * nt_lo; Lr = q0;
    }
    const int m0 = mt << 6;

    const int tid  = threadIdx.x;
    const int wave = tid >> 6, lane = tid & 63;
    const int quad = lane >> 4, l15 = lane & 15;
    const int srow = tid >> 2;                 // K/Q staging row 0..63
    const int vkp  = tid & 31, vhg = tid >> 5; // V staging

    const unsigned short* hq = q + (size_t)bh * T_SEQ * HD;
    const unsigned short* hk = k + (size_t)bh * T_SEQ * HD;
    const unsigned short* hv = v + (size_t)bh * T_SEQ * HD;

    // ---- stage Q tile into Ps, pull A-frags to regs ----
    {
        int m = m0 + srow; if (m > Lr - 1) m = Lr - 1;
        const unsigned short* src = hq + (size_t)(r + m * P) * HD;
#pragma unroll
        for (int rep = 0; rep < 2; ++rep) {
            const int c = ((tid & 3) << 1) + rep;
            int4 a = *(const int4*)(src + (c << 3));
            *(int4*)(Ps + (srow << 6) + ((c ^ (srow & 7)) << 3)) = a;
        }
    }
    __syncthreads();
    short8 qf[2];
#pragma unroll
    for (int ks = 0; ks < 2; ++ks) {
        const int row = (wave << 4) + l15;
        qf[ks] = *(const short8*)(Ps + (row << 6) +
                                  ((((ks << 2) + quad) ^ (row & 7)) << 3));
    }

    floatx4 Oa[4] = {};
    float m_i[4] = {-1e30f, -1e30f, -1e30f, -1e30f};
    float l_i[4] = {0.f, 0.f, 0.f, 0.f};

    for (int kt = 0; kt <= mt; ++kt) {
        const int km0 = kt << 6;

        int mk = km0 + srow; if (mk > Lr - 1) mk = Lr - 1;
        const unsigned short* ksrc = hk + (size_t)(r + mk * P) * HD;
        int4 ka[2];
#pragma unroll
        for (int rep = 0; rep < 2; ++rep)
            ka[rep] = *(const int4*)(ksrc + ((((tid & 3) << 1) + rep) << 3));
        int mv0 = km0 + (vkp << 1);     if (mv0 > Lr - 1) mv0 = Lr - 1;
        int mv1 = km0 + (vkp << 1) + 1; if (mv1 > Lr - 1) mv1 = Lr - 1;
        int4 va = *(const int4*)(hv + (size_t)(r + mv0 * P) * HD + (vhg << 3));
        int4 vb = *(const int4*)(hv + (size_t)(r + mv1 * P) * HD + (vhg << 3));

        __syncthreads();

#pragma unroll
        for (int rep = 0; rep < 2; ++rep) {
            const int c = ((tid & 3) << 1) + rep;
            *(int4*)(Ks + (srow << 6) + ((c ^ (srow & 7)) << 3)) = ka[rep];
        }
        {
            const unsigned short* pa = (const unsigned short*)&va;
            const unsigned short* pb = (const unsigned short*)&vb;
#pragma unroll
            for (int j = 0; j < 8; ++j) {
                const int hd_ = (vhg << 3) + j;
                const unsigned int pk =
                    (unsigned int)pa[j] | ((unsigned int)pb[j] << 16);
                *(unsigned int*)((char*)Vt + (hd_ << 7) +
                                 ((((vkp >> 2) ^ (hd_ & 7)) << 4)) +
                                 ((vkp & 3) << 2)) = pk;
            }
        }
        __syncthreads();

        // ---- QK^T ----
        floatx4 sacc[4] = {};
#pragma unroll
        for (int nt = 0; nt < 4; ++nt) {
            const int row = (nt << 4) + l15;
#pragma unroll
            for (int ks = 0; ks < 2; ++ks) {
                short8 kf = *(const short8*)(Ks + (row << 6) +
                                             ((((ks << 2) + quad) ^ (row & 7)) << 3));
                sacc[nt] = __builtin_amdgcn_mfma_f32_16x16x32_bf16(
                    qf[ks], kf, sacc[nt], 0, 0, 0);
            }
        }

        // ---- scale + causal mask + online softmax ----
        const bool diag = (kt == mt);
        float p[4][4], sc[4];
#pragma unroll
        for (int reg = 0; reg < 4; ++reg) {
            float s[4];
#pragma unroll
            for (int nt = 0; nt < 4; ++nt) s[nt] = sacc[nt][reg] * 0.125f;
            if (diag) {
                const int sq = (wave << 4) + (quad << 2) + reg;
#pragma unroll
                for (int nt = 0; nt < 4; ++nt)
                    if (((nt << 4) + l15) > sq) s[nt] = -1e30f;
            }
            float rm = fmaxf(fmaxf(s[0], s[1]), fmaxf(s[2], s[3]));
            rm = fmaxf(rm, __shfl_xor(rm, 1));
            rm = fmaxf(rm, __shfl_xor(rm, 2));
            rm = fmaxf(rm, __shfl_xor(rm, 4));
            rm = fmaxf(rm, __shfl_xor(rm, 8));
            const float nm = fmaxf(m_i[reg], rm);
            sc[reg] = __expf(m_i[reg] - nm);
            m_i[reg] = nm;
            float ps = 0.f;
#pragma unroll
            for (int nt = 0; nt < 4; ++nt) {
                p[nt][reg] = __expf(s[nt] - nm);
                ps += p[nt][reg];
            }
            ps += __shfl_xor(ps, 1);
            ps += __shfl_xor(ps, 2);
            ps += __shfl_xor(ps, 4);
            ps += __shfl_xor(ps, 8);
            l_i[reg] = l_i[reg] * sc[reg] + ps;
        }

        // ---- P̃ -> Ps (own-wave rows only) ----
#pragma unroll
        for (int reg = 0; reg < 4; ++reg) {
            const int row = (wave << 4) + (quad << 2) + reg;
#pragma unroll
            for (int nt = 0; nt < 4; ++nt) {
                const int col = (nt << 4) + l15;
                *((unsigned short*)((char*)Ps + (row << 7) +
                                    (((col >> 3) ^ (row & 7)) << 4) +
                                    ((col & 7) << 1))) = f2bf(p[nt][reg]);
            }
        }

        // ---- PV ----
        short8 pf[2];
#pragma unroll
        for (int ks = 0; ks < 2; ++ks) {
            const int row = (wave << 4) + l15;
            pf[ks] = *(const short8*)(Ps + (row << 6) +
                                      ((((ks << 2) + quad) ^ (row & 7)) << 3));
        }
#pragma unroll
        for (int nt = 0; nt < 4; ++nt)
#pragma unroll
            for (int reg = 0; reg < 4; ++reg)
                Oa[nt][reg] *= sc[reg];
#pragma unroll
        for (int nt = 0; nt < 4; ++nt) {
            const int row = (nt << 4) + l15;
#pragma unroll
            for (int ks = 0; ks < 2; ++ks) {
                short8 vf = *(const short8*)(Vt + (row << 6) +
                                             ((((ks << 2) + quad) ^ (row & 7)) << 3));
                Oa[nt] = __builtin_amdgcn_mfma_f32_16x16x32_bf16(
                    pf[ks], vf, Oa[nt], 0, 0, 0);
            }
        }
    }

    // ---- epilogue: O through LDS (Ks dead), full-line stores ----
    __syncthreads();          // all waves done reading Ks/Vt
#pragma unroll
    for (int reg = 0; reg < 4; ++reg) {
        const float invl = 1.f / l_i[reg];
        const int row = (wave << 4) + (quad << 2) + reg;
#pragma unroll
        for (int nt = 0; nt < 4; ++nt)
            Ks[(row << 6) + (nt << 4) + l15] = f2bf(Oa[nt][reg] * invl);
    }
    // intra-wave DS ordering: reads below see this wave's writes (own 16 rows)
    {
        const int lrow = lane >> 2;
        const int chk  = (lane & 3) << 1;
        const int ml   = (wave << 4) + lrow;
        const int m    = m0 + ml;
        if (m < Lr) {
            const size_t base = ((size_t)bh * T_SEQ + (r + m * P)) * HD;
            int4 w0 = *(const int4*)(Ks + (ml << 6) + (chk << 3));
            int4 w1 = *(const int4*)(Ks + (ml << 6) + ((chk + 1) << 3));
            *(int4*)(o + base + (chk << 3))       = w0;
            *(int4*)(o + base + ((chk + 1) << 3)) = w1;
        }
    }
}

// ---------------------------------------------------------------------------
// Kernel 3: out projection, bf16 MFMA (A head-major (B,H,T,64) bf16).
// ---------------------------------------------------------------------------
__global__ __launch_bounds__(256) void out_gemm_mfma(
    const unsigned short* __restrict__ A,
    const unsigned short* __restrict__ W,   // 512 x 512 bf16
    const float* __restrict__ bias,
    float* __restrict__ out)
{
    __shared__ unsigned short As[128 * 64];
    __shared__ unsigned short Bs[128 * 64];

    const int tid  = threadIdx.x;
    const int wave = tid >> 6, lane = tid & 63;
    const int quad = lane >> 4, l15 = lane & 15;
    const int wm   = wave >> 1, wn = wave & 1;
    const int row0 = blockIdx.x * 128;
    const int col0 = blockIdx.y * 128;
    const int lr8  = lane >> 3;
    const int sc   = lane & 7;

    floatx4 acc[4][4] = {};

    for (int k0 = 0; k0 < D_MODEL; k0 += 64) {
        const int h = k0 >> 6;
        int4 av[4], bv[4];
#pragma unroll
        for (int i = 0; i < 4; ++i) {
            const int r  = wave * 32 + i * 8 + lr8;
            const int rg = row0 + r;
            const int b = rg >> 11, t = rg & 2047;
            av[i] = *(const int4*)(A + ((((size_t)b << 3) + h) * T_SEQ + t) * HD + (sc << 3));
            bv[i] = *(const int4*)(W + ((size_t)(col0 + r) << 9) + k0 + (sc << 3));
        }
        __syncthreads();
#pragma unroll
        for (int i = 0; i < 4; ++i) {
            const int r  = wave * 32 + i * 8 + lr8;
            const int cp = (sc ^ (r & 7)) << 3;
            *(int4*)(As + (r << 6) + cp) = av[i];
            *(int4*)(Bs + (r << 6) + cp) = bv[i];
        }
        __syncthreads();

#pragma unroll
        for (int ks = 0; ks < 2; ++ks) {
            short8 af[4], bfr[4];
            const int ch = (ks << 2) + quad;
#pragma unroll
            for (int mt = 0; mt < 4; ++mt) {
                const int row = (wm << 6) + (mt << 4) + l15;
                af[mt] = *(const short8*)(As + (row << 6) + ((ch ^ (row & 7)) << 3));
            }
#pragma unroll
            for (int nt = 0; nt < 4; ++nt) {
                const int col = (wn << 6) + (nt << 4) + l15;
                bfr[nt] = *(const short8*)(Bs + (col << 6) + ((ch ^ (col & 7)) << 3));
            }
#pragma unroll
            for (int mt = 0; mt < 4; ++mt)
#pragma unroll
                for (int nt = 0; nt < 4; ++nt)
                    acc[mt][nt] = __builtin_amdgcn_mfma_f32_16x16x32_bf16(
                        af[mt], bfr[nt], acc[mt][nt], 0, 0, 0);
        }
    }

#pragma unroll
    for (int nt = 0; nt < 4; ++nt) {
        const int n = col0 + (wn << 6) + (nt << 4) + l15;
        const float bn = bias[n];
#pragma unroll
        for (int mt = 0; mt < 4; ++mt) {
#pragma unroll
            for (int reg = 0; reg < 4; ++reg) {
                const int m = row0 + (wm << 6) + (mt << 4) + (quad << 2) + reg;
                out[(size_t)m * D_MODEL + n] = acc[mt][nt][reg] + bn;
            }
        }
    }
}

// ---------------------------------------------------------------------------
extern "C" void kernel_launch(void* const* d_in, const int* in_sizes, int n_in,
                              void* d_out, int out_size, void* d_ws, size_t ws_size,
                              hipStream_t stream)
{
    const float* x        = (const float*)d_in[0];
    const int*   periods  = (const int*)  d_in[1];
    const float* in_w     = (const float*)d_in[2];
    const float* in_b     = (const float*)d_in[3];
    const float* out_w    = (const float*)d_in[4];
    const float* out_b    = (const float*)d_in[5];
    float*       out      = (float*)d_out;

    const size_t TENS = (size_t)BATCH * NHEAD * T_SEQ * HD;   // 4,194,304
    unsigned short* qb    = (unsigned short*)d_ws;
    unsigned short* kb    = qb + TENS;
    unsigned short* vb    = kb + TENS;
    unsigned short* xb    = vb + TENS;
    unsigned short* wqkvb = xb + TENS;
    unsigned short* wob   = wqkvb + (size_t)3 * D_MODEL * D_MODEL;
    unsigned short* aob   = xb;   // alias: xb dead after qkv_gemm

    // 0) fp32 -> bf16 conversions
    cvt_bf16<<<(int)(TENS / 8 / 256), 256, 0, stream>>>(x, xb, (int)(TENS / 8));
    cvt_bf16<<<(3 * D_MODEL * D_MODEL / 8) / 256, 256, 0, stream>>>(in_w, wqkvb, 3 * D_MODEL * D_MODEL / 8);
    cvt_bf16<<<(D_MODEL * D_MODEL / 8) / 256, 256, 0, stream>>>(out_w, wob, D_MODEL * D_MODEL / 8);

    // 1) QKV projection (bf16 MFMA), XCD-swizzled flat grid
    qkv_gemm_mfma<<<(M_ROWS / 128) * ((3 * D_MODEL) / 128), 256, 0, stream>>>(
        xb, wqkvb, in_b, qb, kb, vb);

    // 2) residue-class flash attention (MFMA) -> bf16 head-major
    dim3 g2(64, BATCH * NHEAD);
    attn_rc_mfma<<<g2, 256, 0, stream>>>(qb, kb, vb, periods, aob);

    // 3) out projection (bf16 MFMA)
    dim3 g3(M_ROWS / 128, D_MODEL / 128);         // 64 x 4
    out_gemm_mfma<<<g3, 256, 0, stream>>>(aob, wob, out_b, out);
}